// Round 18
// baseline (124.614 us; speedup 1.0000x reference)
//
#include <hip/hip_runtime.h>

typedef unsigned short u16;
typedef __bf16 bf16x8 __attribute__((ext_vector_type(8)));
typedef __bf16 bf16x4 __attribute__((ext_vector_type(4)));
typedef float f32x4 __attribute__((ext_vector_type(4)));
typedef unsigned short u16x4 __attribute__((ext_vector_type(4)));
typedef unsigned short u16x8 __attribute__((ext_vector_type(8)));

__device__ __forceinline__ u16 f2bf(float f) {
  __bf16 h = (__bf16)f;
  return *(u16*)&h;
}

__device__ __forceinline__ f32x4 mfma16(bf16x8 a, bf16x8 b, f32x4 c) {
  return __builtin_amdgcn_mfma_f32_16x16x32_bf16(a, b, c, 0, 0, 0);
}

__device__ __forceinline__ void async16(void* lds, const void* g) {
  __builtin_amdgcn_global_load_lds(
      (const __attribute__((address_space(1))) unsigned int*)g,
      (__attribute__((address_space(3))) unsigned int*)lds, 16, 0, 0);
}

// fold softmax scale AND log2(e) into Wq so softmax uses raw v_exp_f32 (exp2)
#define QSCALE 0.18033688011112042f  // 0.125 * log2(e)

// ---------------------------------------- prep casts + transpose x (merged)
__global__ __launch_bounds__(256) void prep_transpose(
    const float* __restrict__ x, const float* __restrict__ Wq,
    const float* __restrict__ Wkv, const float* __restrict__ Wout,
    const float* __restrict__ ctx, u16* __restrict__ xT,
    u16* __restrict__ Wq_b, u16* __restrict__ Wkv_b,
    u16* __restrict__ Wout_b, u16* __restrict__ ctx_b) {
  __shared__ float tile[64][65];
  int bx = blockIdx.x;
  if (bx < 1024) {
    const long NWQ4 = 512L * 512 / 4, NWKV4 = 1024L * 768 / 4,
               NWOUT4 = 512L * 512 / 4, NCTX4 = 2048L * 768 / 4;
    const long total4 = NWQ4 + NWKV4 + NWOUT4 + NCTX4;
    long stride = 1024L * 256;
    for (long i = (long)bx * 256 + threadIdx.x; i < total4; i += stride) {
      long j = i;
      const float* src;
      u16* dst;
      float sc = 1.0f;
      if (j < NWQ4) { src = Wq; dst = Wq_b; sc = QSCALE; }
      else if ((j -= NWQ4) < NWKV4) { src = Wkv; dst = Wkv_b; }
      else if ((j -= NWKV4) < NWOUT4) { src = Wout; dst = Wout_b; }
      else { j -= NWOUT4; src = ctx; dst = ctx_b; }
      f32x4 v = *(const f32x4*)&src[j * 4];
      u16x4 o;
      #pragma unroll
      for (int r = 0; r < 4; ++r) o[r] = f2bf(v[r] * sc);
      *(u16x4*)&dst[j * 4] = o;
    }
    return;
  }
  bx -= 1024;
  const int p0 = (bx & 63) * 64, c0 = ((bx >> 6) & 7) * 64, b = bx >> 9;
  const float* xb = x + (long)b * (512L * 4096);
  const int ci0 = threadIdx.x >> 4, tx4 = threadIdx.x & 15;
  #pragma unroll
  for (int rep = 0; rep < 4; ++rep) {
    int ci = ci0 + rep * 16;
    f32x4 v = *(const f32x4*)&xb[(long)(c0 + ci) * 4096 + p0 + tx4 * 4];
    #pragma unroll
    for (int r = 0; r < 4; ++r) tile[ci][tx4 * 4 + r] = v[r];
  }
  __syncthreads();
  u16* xTb = xT + (long)b * (4096L * 512);
  const int pi0 = threadIdx.x >> 3, cg = threadIdx.x & 7;
  #pragma unroll
  for (int rep = 0; rep < 2; ++rep) {
    int pi = pi0 + rep * 32;
    u16x8 o;
    #pragma unroll
    for (int j = 0; j < 8; ++j) o[j] = f2bf(tile[cg * 8 + j][pi]);
    *(u16x8*)&xTb[(long)(p0 + pi) * 512 + c0 + cg * 8] = o;
  }
}

// ---------------------------------------------------------------- q+kv GEMM
// (round-16 structure, unchanged — 114.8us best config)
__global__ __launch_bounds__(512, 2) void gemm_qkv(
    const u16* __restrict__ xT, const u16* __restrict__ Wq,
    u16* __restrict__ q, const u16* __restrict__ ctxb,
    const u16* __restrict__ Wkv, u16* __restrict__ kvout) {
  __shared__ u16 pool[2][256 * 64 * 2];   // 128 KB total
  const int t = threadIdx.x, wv = t >> 6, ln = t & 63;
  const int fr = ln & 15, fq = ln >> 4;
  const int L = blockIdx.x;

  if (L < 256) {
    // ---------------- q-proj: 256x256 tile, K=512, nk=8
    const int wr = wv >> 2, wc = wv & 3;
    const int z = L & 7, kq = L >> 3, pr = kq & 1, ld = kq >> 1;
    const int m0 = ld * 256, n0 = pr * 256;
    const int N = 512, K = 512, nk = 8;
    const u16* A = xT + (long)z * (4096L * 512);
    const u16* B = Wq;
    u16* C = q + (long)z * (4096L * 512);

    const u16* aSrc[4];
    const u16* bSrc[4];
    int lbase[4];
    #pragma unroll
    for (int i = 0; i < 4; i++) {
      int c = i * 512 + wv * 64 + ln;
      int row = c >> 3, slot = (c & 7) ^ (row & 7);
      aSrc[i] = A + (long)(m0 + row) * K + slot * 8;
      bSrc[i] = B + (long)(n0 + row) * K + slot * 8;
      lbase[i] = (i * 512 + wv * 64) * 8;
    }

    f32x4 acc[8][4] = {};
    int cur = 0;
    #pragma unroll
    for (int i = 0; i < 4; i++) {
      async16(&pool[0][lbase[i]], aSrc[i]);
      async16(&pool[0][256 * 64 + lbase[i]], bSrc[i]);
    }

    for (int kt = 0; kt < nk; ++kt) {
      if (kt + 1 < nk) {
        const int ko = (kt + 1) * 64;
        #pragma unroll
        for (int i = 0; i < 4; i++) {
          async16(&pool[cur ^ 1][lbase[i]], aSrc[i] + ko);
          async16(&pool[cur ^ 1][256 * 64 + lbase[i]], bSrc[i] + ko);
        }
        asm volatile("s_waitcnt vmcnt(8)" ::: "memory");
      } else {
        asm volatile("s_waitcnt vmcnt(0)" ::: "memory");
      }
      __builtin_amdgcn_s_barrier();
      __builtin_amdgcn_sched_barrier(0);

      const char* Ab = (const char*)&pool[cur][0];
      const char* Bb = (const char*)&pool[cur][256 * 64];
      #pragma unroll
      for (int kk = 0; kk < 2; ++kk) {
        bf16x8 a[8], b[4];
        #pragma unroll
        for (int mf = 0; mf < 8; ++mf) {
          int row = wr * 128 + mf * 16 + fr;
          a[mf] = *(const bf16x8*)(Ab + row * 128 +
                                   ((kk * 64 + fq * 16) ^ ((row & 7) << 4)));
        }
        #pragma unroll
        for (int nf = 0; nf < 4; ++nf) {
          int row = wc * 64 + nf * 16 + fr;
          b[nf] = *(const bf16x8*)(Bb + row * 128 +
                                   ((kk * 64 + fq * 16) ^ ((row & 7) << 4)));
        }
        __builtin_amdgcn_s_setprio(1);
        #pragma unroll
        for (int mf = 0; mf < 8; ++mf)
          #pragma unroll
          for (int nf = 0; nf < 4; ++nf)
            acc[mf][nf] = mfma16(a[mf], b[nf], acc[mf][nf]);
        __builtin_amdgcn_s_setprio(0);
      }
      __builtin_amdgcn_sched_barrier(0);
      __builtin_amdgcn_s_barrier();
      cur ^= 1;
    }

    #pragma unroll
    for (int mf = 0; mf < 8; ++mf)
      #pragma unroll
      for (int r = 0; r < 4; ++r) {
        int grow = m0 + wr * 128 + mf * 16 + fq * 4 + r;
        #pragma unroll
        for (int nf = 0; nf < 4; ++nf) {
          int gcol = n0 + wc * 64 + nf * 16 + fr;
          C[(long)grow * N + gcol] = f2bf(acc[mf][nf][r]);
        }
      }
  } else {
    // ---------------- kv-proj: 128x128 tile, K=768, nk=12, small quantum
    const int wr = wv >> 2, wc = wv & 3;   // wave tile 64x32
    const int L2 = L - 256;
    const int m0 = (L2 & 15) * 128;        // M = 2048
    const int n0 = (L2 >> 4) * 128;        // N = 1024
    const int N = 1024, K = 768, nk = 12;
    const u16* A = ctxb;
    const u16* B = Wkv;
    u16* C = kvout;

    const u16* aSrc[2];
    const u16* bSrc[2];
    int lbase[2];
    #pragma unroll
    for (int i = 0; i < 2; i++) {
      int c = i * 512 + t;
      int row = c >> 3, slot = (c & 7) ^ (row & 7);
      aSrc[i] = A + (long)(m0 + row) * K + slot * 8;
      bSrc[i] = B + (long)(n0 + row) * K + slot * 8;
      lbase[i] = (i * 512 + wv * 64) * 8;
    }

    f32x4 acc[4][2] = {};
    int cur = 0;
    #pragma unroll
    for (int i = 0; i < 2; i++) {
      async16(&pool[0][lbase[i]], aSrc[i]);
      async16(&pool[0][128 * 64 + lbase[i]], bSrc[i]);
    }

    for (int kt = 0; kt < nk; ++kt) {
      if (kt + 1 < nk) {
        const int ko = (kt + 1) * 64;
        #pragma unroll
        for (int i = 0; i < 2; i++) {
          async16(&pool[cur ^ 1][lbase[i]], aSrc[i] + ko);
          async16(&pool[cur ^ 1][128 * 64 + lbase[i]], bSrc[i] + ko);
        }
        asm volatile("s_waitcnt vmcnt(4)" ::: "memory");
      } else {
        asm volatile("s_waitcnt vmcnt(0)" ::: "memory");
      }
      __builtin_amdgcn_s_barrier();
      __builtin_amdgcn_sched_barrier(0);

      const char* Ab = (const char*)&pool[cur][0];
      const char* Bb = (const char*)&pool[cur][128 * 64];
      #pragma unroll
      for (int kk = 0; kk < 2; ++kk) {
        bf16x8 a[4], b[2];
        #pragma unroll
        for (int mf = 0; mf < 4; ++mf) {
          int row = wr * 64 + mf * 16 + fr;
          a[mf] = *(const bf16x8*)(Ab + row * 128 +
                                   ((kk * 64 + fq * 16) ^ ((row & 7) << 4)));
        }
        #pragma unroll
        for (int nf = 0; nf < 2; ++nf) {
          int row = wc * 32 + nf * 16 + fr;
          b[nf] = *(const bf16x8*)(Bb + row * 128 +
                                   ((kk * 64 + fq * 16) ^ ((row & 7) << 4)));
        }
        __builtin_amdgcn_s_setprio(1);
        #pragma unroll
        for (int mf = 0; mf < 4; ++mf)
          #pragma unroll
          for (int nf = 0; nf < 2; ++nf)
            acc[mf][nf] = mfma16(a[mf], b[nf], acc[mf][nf]);
        __builtin_amdgcn_s_setprio(0);
      }
      __builtin_amdgcn_sched_barrier(0);
      __builtin_amdgcn_s_barrier();
      cur ^= 1;
    }

    #pragma unroll
    for (int mf = 0; mf < 4; ++mf)
      #pragma unroll
      for (int r = 0; r < 4; ++r) {
        int grow = m0 + wr * 64 + mf * 16 + fq * 4 + r;
        #pragma unroll
        for (int nf = 0; nf < 2; ++nf) {
          int gcol = n0 + wc * 32 + nf * 16 + fr;
          C[(long)grow * N + gcol] = f2bf(acc[mf][nf][r]);
        }
      }
  }
}

// ---------------------------------------------------------------- out GEMM
// Round-16 best config (256x256, counted-vmcnt, XCD pair decode) +
// NONTEMPORAL epilogue: resid load / out store are single-use 134 MB —
// nt flag keeps them from evicting ao/Wout panels in L2.
__global__ __launch_bounds__(512, 2) void gemm_out(
    const u16* __restrict__ Wout, const u16* __restrict__ ao,
    float* __restrict__ out, const float* __restrict__ bias,
    const float* __restrict__ resid) {
  __shared__ u16 ldsA[2][256 * 64];
  __shared__ u16 ldsB[2][256 * 64];
  const int t = threadIdx.x, wv = t >> 6, ln = t & 63;
  const int wr = wv >> 2, wc = wv & 3, fr = ln & 15, fq = ln >> 4;

  const int L = blockIdx.x;
  const int z = L & 7, kq = L >> 3, pr = kq & 1, ld = kq >> 1;
  const int m0 = pr * 256;
  const int n0 = ld * 256;
  const int N = 4096, K = 512, nk = 8;

  const u16* A = Wout;
  const u16* B = ao + (long)z * (4096L * 512);

  const u16* aSrc[4];
  const u16* bSrc[4];
  int lbase[4];
  #pragma unroll
  for (int i = 0; i < 4; i++) {
    int c = i * 512 + wv * 64 + ln;
    int row = c >> 3, slot = (c & 7) ^ (row & 7);
    aSrc[i] = A + (long)(m0 + row) * K + slot * 8;
    bSrc[i] = B + (long)(n0 + row) * K + slot * 8;
    lbase[i] = (i * 512 + wv * 64) * 8;
  }

  f32x4 acc[8][4] = {};
  int cur = 0;

  #pragma unroll
  for (int i = 0; i < 4; i++) {
    async16(&ldsA[0][lbase[i]], aSrc[i]);
    async16(&ldsB[0][lbase[i]], bSrc[i]);
  }

  for (int kt = 0; kt < nk; ++kt) {
    if (kt + 1 < nk) {
      const int ko = (kt + 1) * 64;
      #pragma unroll
      for (int i = 0; i < 4; i++) {
        async16(&ldsA[cur ^ 1][lbase[i]], aSrc[i] + ko);
        async16(&ldsB[cur ^ 1][lbase[i]], bSrc[i] + ko);
      }
      asm volatile("s_waitcnt vmcnt(8)" ::: "memory");
    } else {
      asm volatile("s_waitcnt vmcnt(0)" ::: "memory");
    }
    __builtin_amdgcn_s_barrier();
    __builtin_amdgcn_sched_barrier(0);

    const char* Ab = (const char*)ldsA[cur];
    const char* Bb = (const char*)ldsB[cur];
    #pragma unroll
    for (int kk = 0; kk < 2; ++kk) {
      bf16x8 a[8], b[4];
      #pragma unroll
      for (int mf = 0; mf < 8; ++mf) {
        int row = wr * 128 + mf * 16 + fr;
        a[mf] = *(const bf16x8*)(Ab + row * 128 +
                                 ((kk * 64 + fq * 16) ^ ((row & 7) << 4)));
      }
      #pragma unroll
      for (int nf = 0; nf < 4; ++nf) {
        int row = wc * 64 + nf * 16 + fr;
        b[nf] = *(const bf16x8*)(Bb + row * 128 +
                                 ((kk * 64 + fq * 16) ^ ((row & 7) << 4)));
      }
      __builtin_amdgcn_s_setprio(1);
      #pragma unroll
      for (int mf = 0; mf < 8; ++mf)
        #pragma unroll
        for (int nf = 0; nf < 4; ++nf)
          acc[mf][nf] = mfma16(a[mf], b[nf], acc[mf][nf]);
      __builtin_amdgcn_s_setprio(0);
    }

    __builtin_amdgcn_sched_barrier(0);
    __builtin_amdgcn_s_barrier();
    cur ^= 1;
  }

  float* Cf = out + (long)z * (512L * 4096);
  const float* Rz = resid + (long)z * (512L * 4096);
  #pragma unroll
  for (int mf = 0; mf < 8; ++mf)
    #pragma unroll
    for (int r = 0; r < 4; ++r) {
      int grow = m0 + wr * 128 + mf * 16 + fq * 4 + r;
      float bv = bias[grow];
      #pragma unroll
      for (int nf = 0; nf < 4; ++nf) {
        int gcol = n0 + wc * 64 + nf * 16 + fr;
        long idx = (long)grow * N + gcol;
        float rv = __builtin_nontemporal_load(&Rz[idx]);
        __builtin_nontemporal_store(acc[mf][nf][r] + bv + rv, &Cf[idx]);
      }
    }
}

// ---------------------------------------------------------------- attention
// Round-13 structure (fused V-transpose), unchanged.
__global__ __launch_bounds__(512) void attn_kernel(
    const u16* __restrict__ q, const u16* __restrict__ kv,
    u16* __restrict__ ao) {
  __shared__ u16 klds[256 * 64];
  __shared__ u16 vlds[64 * 256];
  __shared__ u16 plds[128 * 256];
  const int t = threadIdx.x, w = t >> 6, ln = t & 63;
  const int fr = ln & 15, fq = ln >> 4;
  const int p0 = blockIdx.x * 1024, h = blockIdx.y, b = blockIdx.z;

  const u16* kb = kv + (long)b * 256 * 1024 + h * 64;

  #pragma unroll
  for (int i = 0; i < 4; ++i) {
    int cbase = i * 512 + w * 64;
    int chunk = cbase + ln;
    int row = chunk >> 3, slot = chunk & 7;
    async16(&klds[cbase * 8], kb + (long)row * 1024 + ((slot ^ (row & 7)) << 3));
  }
  {
    char* vw = (char*)vlds;
    const u16* vsrc = kv + (long)b * 256 * 1024 + 512 + h * 64;
    #pragma unroll
    for (int it2 = 0; it2 < 4; ++it2) {
      int id = it2 * 512 + t;
      int n = id >> 3, dg = id & 7;
      bf16x8 v8 = *(const bf16x8*)&vsrc[(long)n * 1024 + dg * 8];
      #pragma unroll
      for (int j = 0; j < 8; ++j) {
        int jj = (j + (ln >> 3)) & 7;
        int d = dg * 8 + jj;
        *(u16*)(vw + ((d * 512 + n * 2) ^ ((d & 7) << 4))) = ((u16*)&v8)[jj];
      }
    }
  }
  __syncthreads();

  const char* kraw = (const char*)klds;
  const char* vraw = (const char*)vlds;
  char* praw = (char*)plds;
  const int prowL = w * 16 + fr;
  const int swz = (fr & 7) << 4;

  const u16* qbase = q + ((long)b * 4096 + p0 + w * 16 + fr) * 512 + h * 64;
  bf16x8 qf0 = *(const bf16x8*)&qbase[fq * 8];
  bf16x8 qf1 = *(const bf16x8*)&qbase[32 + fq * 8];

  for (int it = 0; it < 8; ++it) {
    f32x4 s[16] = {};
    __builtin_amdgcn_s_setprio(1);
    #pragma unroll
    for (int nb = 0; nb < 16; ++nb) {
      int n = nb * 16 + fr;
      bf16x8 kf0 = *(const bf16x8*)(kraw + n * 128 + ((fq * 16) ^ swz));
      bf16x8 kf1 = *(const bf16x8*)(kraw + n * 128 + ((64 + fq * 16) ^ swz));
      s[nb] = mfma16(kf0, qf0, s[nb]);
      s[nb] = mfma16(kf1, qf1, s[nb]);
    }
    __builtin_amdgcn_s_setprio(0);

    const u16* qn = qbase + (long)(((it + 1) & 7) * 128) * 512;
    bf16x8 qn0 = *(const bf16x8*)&qn[fq * 8];
    bf16x8 qn1 = *(const bf16x8*)&qn[32 + fq * 8];

    f32x4 mx = s[0];
    #pragma unroll
    for (int nb = 1; nb < 16; ++nb) {
      mx[0] = fmaxf(mx[0], s[nb][0]); mx[1] = fmaxf(mx[1], s[nb][1]);
      mx[2] = fmaxf(mx[2], s[nb][2]); mx[3] = fmaxf(mx[3], s[nb][3]);
    }
    float m = fmaxf(fmaxf(mx[0], mx[1]), fmaxf(mx[2], mx[3]));
    m = fmaxf(m, __shfl_xor(m, 16));
    m = fmaxf(m, __shfl_xor(m, 32));
    f32x4 sm = {0.f, 0.f, 0.f, 0.f};
    #pragma unroll
    for (int nb = 0; nb < 16; ++nb) {
      #pragma unroll
      for (int r = 0; r < 4; ++r)
        s[nb][r] = __builtin_amdgcn_exp2f(s[nb][r] - m);
      sm += s[nb];
    }
    float sum = (sm[0] + sm[1]) + (sm[2] + sm[3]);
    sum += __shfl_xor(sum, 16);
    sum += __shfl_xor(sum, 32);
    float inv = 1.0f / sum;

    #pragma unroll
    for (int nb = 0; nb < 16; ++nb) {
      bf16x4 pk;
      #pragma unroll
      for (int r = 0; r < 4; ++r) pk[r] = (__bf16)s[nb][r];
      *(bf16x4*)(praw + prowL * 512 + ((nb * 32 + fq * 8) ^ swz)) = pk;
    }
    asm volatile("s_waitcnt lgkmcnt(0)" ::: "memory");
    __builtin_amdgcn_sched_barrier(0);

    f32x4 o[4] = {};
    __builtin_amdgcn_s_setprio(1);
    #pragma unroll
    for (int kk2 = 0; kk2 < 8; ++kk2) {
      bf16x8 pf = *(const bf16x8*)(praw + prowL * 512 + ((kk2 * 64 + fq * 16) ^ swz));
      #pragma unroll
      for (int nfd = 0; nfd < 4; ++nfd) {
        bf16x8 vf = *(const bf16x8*)(vraw + (nfd * 16 + fr) * 512 +
                                     ((kk2 * 64 + fq * 16) ^ swz));
        o[nfd] = mfma16(vf, pf, o[nfd]);
      }
    }
    __builtin_amdgcn_s_setprio(0);

    u16* aob = ao + ((long)b * 4096 + p0 + it * 128 + w * 16 + fr) * 512 + h * 64;
    #pragma unroll
    for (int nfd = 0; nfd < 4; ++nfd) {
      bf16x4 ov;
      #pragma unroll
      for (int r = 0; r < 4; ++r) ov[r] = (__bf16)(o[nfd][r] * inv);
      *(bf16x4*)(aob + nfd * 16 + fq * 4) = ov;
    }
    qf0 = qn0;
    qf1 = qn1;
  }
}

// ---------------------------------------------------------------- launch
extern "C" void kernel_launch(void* const* d_in, const int* in_sizes, int n_in,
                              void* d_out, int out_size, void* d_ws, size_t ws_size,
                              hipStream_t stream) {
  const float* x    = (const float*)d_in[0];
  const float* ctx  = (const float*)d_in[1];
  const float* Wq   = (const float*)d_in[2];
  const float* Wkv  = (const float*)d_in[3];
  const float* Wout = (const float*)d_in[4];
  const float* bout = (const float*)d_in[5];
  float* out = (float*)d_out;
  char* ws = (char*)d_ws;

  u16* xT     = (u16*)(ws);              // 33,554,432 B (reused as ao)
  u16* q      = (u16*)(ws + 33554432);   // 33,554,432 B
  u16* kv     = (u16*)(ws + 67108864);   //  4,194,304 B
  u16* Wq_b   = (u16*)(ws + 73400320);   //    524,288 B
  u16* Wkv_b  = (u16*)(ws + 73924608);   //  1,572,864 B
  u16* Wout_b = (u16*)(ws + 75497472);   //    524,288 B
  u16* ctx_b  = (u16*)(ws + 76021760);   //  3,145,728 B
  u16* ao     = xT;

  prep_transpose<<<dim3(5120), dim3(256), 0, stream>>>(
      x, Wq, Wkv, Wout, ctx, xT, Wq_b, Wkv_b, Wout_b, ctx_b);
  // q-proj (256 blocks, gen 1) + kv-proj (128 small blocks, cheap tail)
  gemm_qkv<<<dim3(384), dim3(512), 0, stream>>>(
      xT, Wq_b, q, ctx_b, Wkv_b, kv);
  attn_kernel<<<dim3(4, 8, 8), dim3(512), 0, stream>>>(q, kv, ao);
  gemm_out<<<dim3(256), dim3(512), 0, stream>>>(
      Wout_b, ao, out, bout, x);
}

// Round 19
// 114.792 us; speedup vs baseline: 1.0856x; 1.0856x over previous
//
#include <hip/hip_runtime.h>

typedef unsigned short u16;
typedef __bf16 bf16x8 __attribute__((ext_vector_type(8)));
typedef __bf16 bf16x4 __attribute__((ext_vector_type(4)));
typedef float f32x4 __attribute__((ext_vector_type(4)));
typedef unsigned short u16x4 __attribute__((ext_vector_type(4)));
typedef unsigned short u16x8 __attribute__((ext_vector_type(8)));

__device__ __forceinline__ u16 f2bf(float f) {
  __bf16 h = (__bf16)f;
  return *(u16*)&h;
}

__device__ __forceinline__ f32x4 mfma16(bf16x8 a, bf16x8 b, f32x4 c) {
  return __builtin_amdgcn_mfma_f32_16x16x32_bf16(a, b, c, 0, 0, 0);
}

__device__ __forceinline__ void async16(void* lds, const void* g) {
  __builtin_amdgcn_global_load_lds(
      (const __attribute__((address_space(1))) unsigned int*)g,
      (__attribute__((address_space(3))) unsigned int*)lds, 16, 0, 0);
}

// fold softmax scale AND log2(e) into Wq so softmax uses raw v_exp_f32 (exp2)
#define QSCALE 0.18033688011112042f  // 0.125 * log2(e)

// ---------------------------------------- prep casts + transpose x (merged)
__global__ __launch_bounds__(256) void prep_transpose(
    const float* __restrict__ x, const float* __restrict__ Wq,
    const float* __restrict__ Wkv, const float* __restrict__ Wout,
    const float* __restrict__ ctx, u16* __restrict__ xT,
    u16* __restrict__ Wq_b, u16* __restrict__ Wkv_b,
    u16* __restrict__ Wout_b, u16* __restrict__ ctx_b) {
  __shared__ float tile[64][65];
  int bx = blockIdx.x;
  if (bx < 1024) {
    const long NWQ4 = 512L * 512 / 4, NWKV4 = 1024L * 768 / 4,
               NWOUT4 = 512L * 512 / 4, NCTX4 = 2048L * 768 / 4;
    const long total4 = NWQ4 + NWKV4 + NWOUT4 + NCTX4;
    long stride = 1024L * 256;
    for (long i = (long)bx * 256 + threadIdx.x; i < total4; i += stride) {
      long j = i;
      const float* src;
      u16* dst;
      float sc = 1.0f;
      if (j < NWQ4) { src = Wq; dst = Wq_b; sc = QSCALE; }
      else if ((j -= NWQ4) < NWKV4) { src = Wkv; dst = Wkv_b; }
      else if ((j -= NWKV4) < NWOUT4) { src = Wout; dst = Wout_b; }
      else { j -= NWOUT4; src = ctx; dst = ctx_b; }
      f32x4 v = *(const f32x4*)&src[j * 4];
      u16x4 o;
      #pragma unroll
      for (int r = 0; r < 4; ++r) o[r] = f2bf(v[r] * sc);
      *(u16x4*)&dst[j * 4] = o;
    }
    return;
  }
  bx -= 1024;
  const int p0 = (bx & 63) * 64, c0 = ((bx >> 6) & 7) * 64, b = bx >> 9;
  const float* xb = x + (long)b * (512L * 4096);
  const int ci0 = threadIdx.x >> 4, tx4 = threadIdx.x & 15;
  #pragma unroll
  for (int rep = 0; rep < 4; ++rep) {
    int ci = ci0 + rep * 16;
    f32x4 v = *(const f32x4*)&xb[(long)(c0 + ci) * 4096 + p0 + tx4 * 4];
    #pragma unroll
    for (int r = 0; r < 4; ++r) tile[ci][tx4 * 4 + r] = v[r];
  }
  __syncthreads();
  u16* xTb = xT + (long)b * (4096L * 512);
  const int pi0 = threadIdx.x >> 3, cg = threadIdx.x & 7;
  #pragma unroll
  for (int rep = 0; rep < 2; ++rep) {
    int pi = pi0 + rep * 32;
    u16x8 o;
    #pragma unroll
    for (int j = 0; j < 8; ++j) o[j] = f2bf(tile[cg * 8 + j][pi]);
    *(u16x8*)&xTb[(long)(p0 + pi) * 512 + c0 + cg * 8] = o;
  }
}

// ---------------------------------------------------------------- q+kv GEMM
// (round-16 structure, unchanged — 114.8us best config)
__global__ __launch_bounds__(512, 2) void gemm_qkv(
    const u16* __restrict__ xT, const u16* __restrict__ Wq,
    u16* __restrict__ q, const u16* __restrict__ ctxb,
    const u16* __restrict__ Wkv, u16* __restrict__ kvout) {
  __shared__ u16 pool[2][256 * 64 * 2];   // 128 KB total
  const int t = threadIdx.x, wv = t >> 6, ln = t & 63;
  const int fr = ln & 15, fq = ln >> 4;
  const int L = blockIdx.x;

  if (L < 256) {
    // ---------------- q-proj: 256x256 tile, K=512, nk=8
    const int wr = wv >> 2, wc = wv & 3;
    const int z = L & 7, kq = L >> 3, pr = kq & 1, ld = kq >> 1;
    const int m0 = ld * 256, n0 = pr * 256;
    const int N = 512, K = 512, nk = 8;
    const u16* A = xT + (long)z * (4096L * 512);
    const u16* B = Wq;
    u16* C = q + (long)z * (4096L * 512);

    const u16* aSrc[4];
    const u16* bSrc[4];
    int lbase[4];
    #pragma unroll
    for (int i = 0; i < 4; i++) {
      int c = i * 512 + wv * 64 + ln;
      int row = c >> 3, slot = (c & 7) ^ (row & 7);
      aSrc[i] = A + (long)(m0 + row) * K + slot * 8;
      bSrc[i] = B + (long)(n0 + row) * K + slot * 8;
      lbase[i] = (i * 512 + wv * 64) * 8;
    }

    f32x4 acc[8][4] = {};
    int cur = 0;
    #pragma unroll
    for (int i = 0; i < 4; i++) {
      async16(&pool[0][lbase[i]], aSrc[i]);
      async16(&pool[0][256 * 64 + lbase[i]], bSrc[i]);
    }

    for (int kt = 0; kt < nk; ++kt) {
      if (kt + 1 < nk) {
        const int ko = (kt + 1) * 64;
        #pragma unroll
        for (int i = 0; i < 4; i++) {
          async16(&pool[cur ^ 1][lbase[i]], aSrc[i] + ko);
          async16(&pool[cur ^ 1][256 * 64 + lbase[i]], bSrc[i] + ko);
        }
        asm volatile("s_waitcnt vmcnt(8)" ::: "memory");
      } else {
        asm volatile("s_waitcnt vmcnt(0)" ::: "memory");
      }
      __builtin_amdgcn_s_barrier();
      __builtin_amdgcn_sched_barrier(0);

      const char* Ab = (const char*)&pool[cur][0];
      const char* Bb = (const char*)&pool[cur][256 * 64];
      #pragma unroll
      for (int kk = 0; kk < 2; ++kk) {
        bf16x8 a[8], b[4];
        #pragma unroll
        for (int mf = 0; mf < 8; ++mf) {
          int row = wr * 128 + mf * 16 + fr;
          a[mf] = *(const bf16x8*)(Ab + row * 128 +
                                   ((kk * 64 + fq * 16) ^ ((row & 7) << 4)));
        }
        #pragma unroll
        for (int nf = 0; nf < 4; ++nf) {
          int row = wc * 64 + nf * 16 + fr;
          b[nf] = *(const bf16x8*)(Bb + row * 128 +
                                   ((kk * 64 + fq * 16) ^ ((row & 7) << 4)));
        }
        __builtin_amdgcn_s_setprio(1);
        #pragma unroll
        for (int mf = 0; mf < 8; ++mf)
          #pragma unroll
          for (int nf = 0; nf < 4; ++nf)
            acc[mf][nf] = mfma16(a[mf], b[nf], acc[mf][nf]);
        __builtin_amdgcn_s_setprio(0);
      }
      __builtin_amdgcn_sched_barrier(0);
      __builtin_amdgcn_s_barrier();
      cur ^= 1;
    }

    #pragma unroll
    for (int mf = 0; mf < 8; ++mf)
      #pragma unroll
      for (int r = 0; r < 4; ++r) {
        int grow = m0 + wr * 128 + mf * 16 + fq * 4 + r;
        #pragma unroll
        for (int nf = 0; nf < 4; ++nf) {
          int gcol = n0 + wc * 64 + nf * 16 + fr;
          C[(long)grow * N + gcol] = f2bf(acc[mf][nf][r]);
        }
      }
  } else {
    // ---------------- kv-proj: 128x128 tile, K=768, nk=12, small quantum
    const int wr = wv >> 2, wc = wv & 3;   // wave tile 64x32
    const int L2 = L - 256;
    const int m0 = (L2 & 15) * 128;        // M = 2048
    const int n0 = (L2 >> 4) * 128;        // N = 1024
    const int N = 1024, K = 768, nk = 12;
    const u16* A = ctxb;
    const u16* B = Wkv;
    u16* C = kvout;

    const u16* aSrc[2];
    const u16* bSrc[2];
    int lbase[2];
    #pragma unroll
    for (int i = 0; i < 2; i++) {
      int c = i * 512 + t;
      int row = c >> 3, slot = (c & 7) ^ (row & 7);
      aSrc[i] = A + (long)(m0 + row) * K + slot * 8;
      bSrc[i] = B + (long)(n0 + row) * K + slot * 8;
      lbase[i] = (i * 512 + wv * 64) * 8;
    }

    f32x4 acc[4][2] = {};
    int cur = 0;
    #pragma unroll
    for (int i = 0; i < 2; i++) {
      async16(&pool[0][lbase[i]], aSrc[i]);
      async16(&pool[0][128 * 64 + lbase[i]], bSrc[i]);
    }

    for (int kt = 0; kt < nk; ++kt) {
      if (kt + 1 < nk) {
        const int ko = (kt + 1) * 64;
        #pragma unroll
        for (int i = 0; i < 2; i++) {
          async16(&pool[cur ^ 1][lbase[i]], aSrc[i] + ko);
          async16(&pool[cur ^ 1][128 * 64 + lbase[i]], bSrc[i] + ko);
        }
        asm volatile("s_waitcnt vmcnt(4)" ::: "memory");
      } else {
        asm volatile("s_waitcnt vmcnt(0)" ::: "memory");
      }
      __builtin_amdgcn_s_barrier();
      __builtin_amdgcn_sched_barrier(0);

      const char* Ab = (const char*)&pool[cur][0];
      const char* Bb = (const char*)&pool[cur][128 * 64];
      #pragma unroll
      for (int kk = 0; kk < 2; ++kk) {
        bf16x8 a[4], b[2];
        #pragma unroll
        for (int mf = 0; mf < 4; ++mf) {
          int row = wr * 64 + mf * 16 + fr;
          a[mf] = *(const bf16x8*)(Ab + row * 128 +
                                   ((kk * 64 + fq * 16) ^ ((row & 7) << 4)));
        }
        #pragma unroll
        for (int nf = 0; nf < 2; ++nf) {
          int row = wc * 32 + nf * 16 + fr;
          b[nf] = *(const bf16x8*)(Bb + row * 128 +
                                   ((kk * 64 + fq * 16) ^ ((row & 7) << 4)));
        }
        __builtin_amdgcn_s_setprio(1);
        #pragma unroll
        for (int mf = 0; mf < 4; ++mf)
          #pragma unroll
          for (int nf = 0; nf < 2; ++nf)
            acc[mf][nf] = mfma16(a[mf], b[nf], acc[mf][nf]);
        __builtin_amdgcn_s_setprio(0);
      }
      __builtin_amdgcn_sched_barrier(0);
      __builtin_amdgcn_s_barrier();
      cur ^= 1;
    }

    #pragma unroll
    for (int mf = 0; mf < 4; ++mf)
      #pragma unroll
      for (int r = 0; r < 4; ++r) {
        int grow = m0 + wr * 64 + mf * 16 + fq * 4 + r;
        #pragma unroll
        for (int nf = 0; nf < 2; ++nf) {
          int gcol = n0 + wc * 32 + nf * 16 + fr;
          C[(long)grow * N + gcol] = f2bf(acc[mf][nf][r]);
        }
      }
  }
}

// ---------------------------------------------------------------- out GEMM
// Round-8 nt256 counted-vmcnt + XCD pair decode (pair shares ao B-panel).
__global__ __launch_bounds__(512, 2) void gemm_out(
    const u16* __restrict__ Wout, const u16* __restrict__ ao,
    float* __restrict__ out, const float* __restrict__ bias,
    const float* __restrict__ resid) {
  __shared__ u16 ldsA[2][256 * 64];
  __shared__ u16 ldsB[2][256 * 64];
  const int t = threadIdx.x, wv = t >> 6, ln = t & 63;
  const int wr = wv >> 2, wc = wv & 3, fr = ln & 15, fq = ln >> 4;

  const int L = blockIdx.x;
  const int z = L & 7, kq = L >> 3, pr = kq & 1, ld = kq >> 1;
  const int m0 = pr * 256;
  const int n0 = ld * 256;
  const int N = 4096, K = 512, nk = 8;

  const u16* A = Wout;
  const u16* B = ao + (long)z * (4096L * 512);

  const u16* aSrc[4];
  const u16* bSrc[4];
  int lbase[4];
  #pragma unroll
  for (int i = 0; i < 4; i++) {
    int c = i * 512 + wv * 64 + ln;
    int row = c >> 3, slot = (c & 7) ^ (row & 7);
    aSrc[i] = A + (long)(m0 + row) * K + slot * 8;
    bSrc[i] = B + (long)(n0 + row) * K + slot * 8;
    lbase[i] = (i * 512 + wv * 64) * 8;
  }

  f32x4 acc[8][4] = {};
  int cur = 0;

  #pragma unroll
  for (int i = 0; i < 4; i++) {
    async16(&ldsA[0][lbase[i]], aSrc[i]);
    async16(&ldsB[0][lbase[i]], bSrc[i]);
  }

  for (int kt = 0; kt < nk; ++kt) {
    if (kt + 1 < nk) {
      const int ko = (kt + 1) * 64;
      #pragma unroll
      for (int i = 0; i < 4; i++) {
        async16(&ldsA[cur ^ 1][lbase[i]], aSrc[i] + ko);
        async16(&ldsB[cur ^ 1][lbase[i]], bSrc[i] + ko);
      }
      asm volatile("s_waitcnt vmcnt(8)" ::: "memory");
    } else {
      asm volatile("s_waitcnt vmcnt(0)" ::: "memory");
    }
    __builtin_amdgcn_s_barrier();
    __builtin_amdgcn_sched_barrier(0);

    const char* Ab = (const char*)ldsA[cur];
    const char* Bb = (const char*)ldsB[cur];
    #pragma unroll
    for (int kk = 0; kk < 2; ++kk) {
      bf16x8 a[8], b[4];
      #pragma unroll
      for (int mf = 0; mf < 8; ++mf) {
        int row = wr * 128 + mf * 16 + fr;
        a[mf] = *(const bf16x8*)(Ab + row * 128 +
                                 ((kk * 64 + fq * 16) ^ ((row & 7) << 4)));
      }
      #pragma unroll
      for (int nf = 0; nf < 4; ++nf) {
        int row = wc * 64 + nf * 16 + fr;
        b[nf] = *(const bf16x8*)(Bb + row * 128 +
                                 ((kk * 64 + fq * 16) ^ ((row & 7) << 4)));
      }
      __builtin_amdgcn_s_setprio(1);
      #pragma unroll
      for (int mf = 0; mf < 8; ++mf)
        #pragma unroll
        for (int nf = 0; nf < 4; ++nf)
          acc[mf][nf] = mfma16(a[mf], b[nf], acc[mf][nf]);
      __builtin_amdgcn_s_setprio(0);
    }

    __builtin_amdgcn_sched_barrier(0);
    __builtin_amdgcn_s_barrier();
    cur ^= 1;
  }

  float* Cf = out + (long)z * (512L * 4096);
  const float* Rz = resid + (long)z * (512L * 4096);
  #pragma unroll
  for (int mf = 0; mf < 8; ++mf)
    #pragma unroll
    for (int r = 0; r < 4; ++r) {
      int grow = m0 + wr * 128 + mf * 16 + fq * 4 + r;
      float bv = bias[grow];
      #pragma unroll
      for (int nf = 0; nf < 4; ++nf) {
        int gcol = n0 + wc * 64 + nf * 16 + fr;
        long idx = (long)grow * N + gcol;
        Cf[idx] = acc[mf][nf][r] + bv + Rz[idx];
      }
    }
}

// ---------------------------------------------------------------- attention
// Round-13 structure (fused V-transpose), unchanged.
__global__ __launch_bounds__(512) void attn_kernel(
    const u16* __restrict__ q, const u16* __restrict__ kv,
    u16* __restrict__ ao) {
  __shared__ u16 klds[256 * 64];
  __shared__ u16 vlds[64 * 256];
  __shared__ u16 plds[128 * 256];
  const int t = threadIdx.x, w = t >> 6, ln = t & 63;
  const int fr = ln & 15, fq = ln >> 4;
  const int p0 = blockIdx.x * 1024, h = blockIdx.y, b = blockIdx.z;

  const u16* kb = kv + (long)b * 256 * 1024 + h * 64;

  #pragma unroll
  for (int i = 0; i < 4; ++i) {
    int cbase = i * 512 + w * 64;
    int chunk = cbase + ln;
    int row = chunk >> 3, slot = chunk & 7;
    async16(&klds[cbase * 8], kb + (long)row * 1024 + ((slot ^ (row & 7)) << 3));
  }
  {
    char* vw = (char*)vlds;
    const u16* vsrc = kv + (long)b * 256 * 1024 + 512 + h * 64;
    #pragma unroll
    for (int it2 = 0; it2 < 4; ++it2) {
      int id = it2 * 512 + t;
      int n = id >> 3, dg = id & 7;
      bf16x8 v8 = *(const bf16x8*)&vsrc[(long)n * 1024 + dg * 8];
      #pragma unroll
      for (int j = 0; j < 8; ++j) {
        int jj = (j + (ln >> 3)) & 7;
        int d = dg * 8 + jj;
        *(u16*)(vw + ((d * 512 + n * 2) ^ ((d & 7) << 4))) = ((u16*)&v8)[jj];
      }
    }
  }
  __syncthreads();

  const char* kraw = (const char*)klds;
  const char* vraw = (const char*)vlds;
  char* praw = (char*)plds;
  const int prowL = w * 16 + fr;
  const int swz = (fr & 7) << 4;

  const u16* qbase = q + ((long)b * 4096 + p0 + w * 16 + fr) * 512 + h * 64;
  bf16x8 qf0 = *(const bf16x8*)&qbase[fq * 8];
  bf16x8 qf1 = *(const bf16x8*)&qbase[32 + fq * 8];

  for (int it = 0; it < 8; ++it) {
    f32x4 s[16] = {};
    __builtin_amdgcn_s_setprio(1);
    #pragma unroll
    for (int nb = 0; nb < 16; ++nb) {
      int n = nb * 16 + fr;
      bf16x8 kf0 = *(const bf16x8*)(kraw + n * 128 + ((fq * 16) ^ swz));
      bf16x8 kf1 = *(const bf16x8*)(kraw + n * 128 + ((64 + fq * 16) ^ swz));
      s[nb] = mfma16(kf0, qf0, s[nb]);
      s[nb] = mfma16(kf1, qf1, s[nb]);
    }
    __builtin_amdgcn_s_setprio(0);

    const u16* qn = qbase + (long)(((it + 1) & 7) * 128) * 512;
    bf16x8 qn0 = *(const bf16x8*)&qn[fq * 8];
    bf16x8 qn1 = *(const bf16x8*)&qn[32 + fq * 8];

    f32x4 mx = s[0];
    #pragma unroll
    for (int nb = 1; nb < 16; ++nb) {
      mx[0] = fmaxf(mx[0], s[nb][0]); mx[1] = fmaxf(mx[1], s[nb][1]);
      mx[2] = fmaxf(mx[2], s[nb][2]); mx[3] = fmaxf(mx[3], s[nb][3]);
    }
    float m = fmaxf(fmaxf(mx[0], mx[1]), fmaxf(mx[2], mx[3]));
    m = fmaxf(m, __shfl_xor(m, 16));
    m = fmaxf(m, __shfl_xor(m, 32));
    f32x4 sm = {0.f, 0.f, 0.f, 0.f};
    #pragma unroll
    for (int nb = 0; nb < 16; ++nb) {
      #pragma unroll
      for (int r = 0; r < 4; ++r)
        s[nb][r] = __builtin_amdgcn_exp2f(s[nb][r] - m);
      sm += s[nb];
    }
    float sum = (sm[0] + sm[1]) + (sm[2] + sm[3]);
    sum += __shfl_xor(sum, 16);
    sum += __shfl_xor(sum, 32);
    float inv = 1.0f / sum;

    #pragma unroll
    for (int nb = 0; nb < 16; ++nb) {
      bf16x4 pk;
      #pragma unroll
      for (int r = 0; r < 4; ++r) pk[r] = (__bf16)s[nb][r];
      *(bf16x4*)(praw + prowL * 512 + ((nb * 32 + fq * 8) ^ swz)) = pk;
    }
    asm volatile("s_waitcnt lgkmcnt(0)" ::: "memory");
    __builtin_amdgcn_sched_barrier(0);

    f32x4 o[4] = {};
    __builtin_amdgcn_s_setprio(1);
    #pragma unroll
    for (int kk2 = 0; kk2 < 8; ++kk2) {
      bf16x8 pf = *(const bf16x8*)(praw + prowL * 512 + ((kk2 * 64 + fq * 16) ^ swz));
      #pragma unroll
      for (int nfd = 0; nfd < 4; ++nfd) {
        bf16x8 vf = *(const bf16x8*)(vraw + (nfd * 16 + fr) * 512 +
                                     ((kk2 * 64 + fq * 16) ^ swz));
        o[nfd] = mfma16(vf, pf, o[nfd]);
      }
    }
    __builtin_amdgcn_s_setprio(0);

    u16* aob = ao + ((long)b * 4096 + p0 + it * 128 + w * 16 + fr) * 512 + h * 64;
    #pragma unroll
    for (int nfd = 0; nfd < 4; ++nfd) {
      bf16x4 ov;
      #pragma unroll
      for (int r = 0; r < 4; ++r) ov[r] = (__bf16)(o[nfd][r] * inv);
      *(bf16x4*)(aob + nfd * 16 + fq * 4) = ov;
    }
    qf0 = qn0;
    qf1 = qn1;
  }
}

// ---------------------------------------------------------------- launch
extern "C" void kernel_launch(void* const* d_in, const int* in_sizes, int n_in,
                              void* d_out, int out_size, void* d_ws, size_t ws_size,
                              hipStream_t stream) {
  const float* x    = (const float*)d_in[0];
  const float* ctx  = (const float*)d_in[1];
  const float* Wq   = (const float*)d_in[2];
  const float* Wkv  = (const float*)d_in[3];
  const float* Wout = (const float*)d_in[4];
  const float* bout = (const float*)d_in[5];
  float* out = (float*)d_out;
  char* ws = (char*)d_ws;

  u16* xT     = (u16*)(ws);              // 33,554,432 B (reused as ao)
  u16* q      = (u16*)(ws + 33554432);   // 33,554,432 B
  u16* kv     = (u16*)(ws + 67108864);   //  4,194,304 B
  u16* Wq_b   = (u16*)(ws + 73400320);   //    524,288 B
  u16* Wkv_b  = (u16*)(ws + 73924608);   //  1,572,864 B
  u16* Wout_b = (u16*)(ws + 75497472);   //    524,288 B
  u16* ctx_b  = (u16*)(ws + 76021760);   //  3,145,728 B
  u16* ao     = xT;

  prep_transpose<<<dim3(5120), dim3(256), 0, stream>>>(
      x, Wq, Wkv, Wout, ctx, xT, Wq_b, Wkv_b, Wout_b, ctx_b);
  // q-proj (256 blocks, gen 1) + kv-proj (128 small blocks, cheap tail)
  gemm_qkv<<<dim3(384), dim3(512), 0, stream>>>(
      xT, Wq_b, q, ctx_b, Wkv_b, kv);
  attn_kernel<<<dim3(4, 8, 8), dim3(512), 0, stream>>>(q, kv, ao);
  gemm_out<<<dim3(256), dim3(512), 0, stream>>>(
      Wout_b, ao, out, bout, x);
}